// Round 9
// baseline (13071.082 us; speedup 1.0000x reference)
//
#include <hip/hip_runtime.h>
#include <hip/hip_bf16.h>

#define TL 2048
#define NB 64
#define NH 64
#define NLAY 10
#define NRESU 3
#define RSTEP 64

typedef float f32x4 __attribute__((ext_vector_type(4)));
typedef unsigned u32x4 __attribute__((ext_vector_type(4)));
typedef short bhalf8 __attribute__((ext_vector_type(8)));
typedef short bhalf4 __attribute__((ext_vector_type(4)));

__device__ __forceinline__ unsigned short f2bf(float f) {
    unsigned u = __float_as_uint(f);
    unsigned r = u + 0x7fffu + ((u >> 16) & 1u);
    return (unsigned short)(r >> 16);
}
__device__ __forceinline__ float bf2f(unsigned short h) {
    return __uint_as_float(((unsigned)h) << 16);
}
__device__ __forceinline__ float fast_sigmoid(float x) {
    return __builtin_amdgcn_rcpf(1.0f + __expf(-x));
}
__device__ __forceinline__ float fast_tanh(float x) {
    float e = __expf(2.0f * x);
    return 1.0f - 2.0f * __builtin_amdgcn_rcpf(e + 1.0f);
}

// ---------------- frontend ----------------
__global__ __launch_bounds__(256) void k_frontend(
    const float* __restrict__ in,
    const float* __restrict__ c1w, const float* __restrict__ c1b,
    const float* __restrict__ c2w, const float* __restrict__ c2b,
    float* __restrict__ x0)
{
    __shared__ float s_c1w[128];
    __shared__ float s_c1b[32];
    __shared__ float s_c2w[64 * 33];
    __shared__ float s_c2b[64];
    __shared__ float h1[64 * 33];
    __shared__ float ot[64 * 65];
    int tid = threadIdx.x;
    int b = blockIdx.x >> 5;
    int l0 = (blockIdx.x & 31) << 6;
    if (tid < 128) s_c1w[tid] = c1w[tid];
    if (tid < 32) s_c1b[tid] = c1b[tid];
    if (tid < 64) s_c2b[tid] = c2b[tid];
    for (int r = tid; r < 2048; r += 256) s_c2w[(r >> 5) * 33 + (r & 31)] = c2w[r];
    __syncthreads();
    if (tid < 64) {
        const float* ip = in + ((size_t)b * TL + l0 + tid) * 4;
        float x0v = ip[0], x1 = ip[1], x2 = ip[2], x3 = ip[3];
#pragma unroll
        for (int o = 0; o < 32; o++) {
            float a = s_c1w[o * 4 + 0] * x0v + s_c1w[o * 4 + 1] * x1 +
                      s_c1w[o * 4 + 2] * x2 + s_c1w[o * 4 + 3] * x3 + s_c1b[o];
            h1[tid * 33 + o] = fmaxf(a, 0.0f);
        }
    }
    __syncthreads();
    {
        int o = tid & 63, lg = tid >> 6;
#pragma unroll
        for (int j = 0; j < 16; j++) {
            int l = lg * 16 + j;
            float a = s_c2b[o];
#pragma unroll
            for (int i = 0; i < 32; i++) a += h1[l * 33 + i] * s_c2w[o * 33 + i];
            ot[o * 65 + l] = fmaxf(a, 0.0f);
        }
    }
    __syncthreads();
    for (int r = 0; r < 16; r++) {
        int idx = tid + 256 * r;
        int c = idx >> 6, l = idx & 63;
        x0[((size_t)b * 64 + c) * TL + l0 + l] = ot[c * 65 + l];
    }
}

// ---------------- weight transpose for resconv ----------------
__global__ __launch_bounds__(256) void k_prepw(const float* __restrict__ w, float* __restrict__ wt)
{
    int idx = blockIdx.x * 256 + threadIdx.x;
    if (idx >= NRESU * 64 * 64 * 11) return;
    int k = idx % 11;
    int rest = idx / 11;
    int i = rest & 63;
    int o = (rest >> 6) & 63;
    int uu = rest >> 12;
    wt[(((size_t)uu * 64 + i) * 11 + k) * 64 + o] = w[idx];
}

// ---------------- residual conv k=11 pad=5 ----------------
__global__ __launch_bounds__(256) void k_resconv(
    const float* __restrict__ in, float* __restrict__ out,
    const float* __restrict__ wt, const float* __restrict__ bias,
    const float* __restrict__ bg, const float* __restrict__ bb,
    const float* __restrict__ bm, const float* __restrict__ bv,
    int accumulate)
{
    __shared__ float sscale[64], sshift[64];
    __shared__ float ht[64 * 139];
    int tid = threadIdx.x;
    int b = blockIdx.x >> 4;
    int l0 = (blockIdx.x & 15) << 7;
    if (tid < 64) {
        float sc = bg[tid] * rsqrtf(bv[tid] + 1e-5f);
        sscale[tid] = sc;
        sshift[tid] = bb[tid] - bm[tid] * sc;
    }
    __syncthreads();
    for (int r = 0; r < 35; r++) {
        int idx = tid + 256 * r;
        if (idx < 64 * 138) {
            int i = idx / 138, ll = idx - i * 138;
            int l = l0 - 5 + ll;
            float v = 0.0f;
            if (l >= 0 && l < TL) v = in[((size_t)b * 64 + i) * TL + l];
            ht[i * 139 + ll] = fmaxf(v * sscale[i] + sshift[i], 0.0f);
        }
    }
    __syncthreads();
    int o = tid & 63, lq = tid >> 6;
    float acc[32];
#pragma unroll
    for (int j = 0; j < 32; j++) acc[j] = 0.0f;
    for (int i = 0; i < 64; i++) {
        float wr[11];
#pragma unroll
        for (int k = 0; k < 11; k++) wr[k] = wt[(i * 11 + k) * 64 + o];
        float hr[42];
        const float* hp = ht + i * 139 + lq * 32;
#pragma unroll
        for (int k = 0; k < 42; k++) hr[k] = hp[k];
#pragma unroll
        for (int k = 0; k < 11; k++)
#pragma unroll
            for (int j = 0; j < 32; j++) acc[j] += hr[k + j] * wr[k];
    }
    float bsv = bias[o];
    float* op = out + ((size_t)b * 64 + o) * TL + l0 + lq * 32;
    if (accumulate) {
#pragma unroll
        for (int j = 0; j < 32; j++) op[j] += acc[j] + bsv;
    } else {
#pragma unroll
        for (int j = 0; j < 32; j++) op[j] = acc[j] + bsv;
    }
}

// ---------------- transpose [NB][64][TL] -> [TL][NB][64] ----------------
__global__ __launch_bounds__(256) void k_transpose(
    const float* __restrict__ x0, float* __restrict__ X)
{
    __shared__ float t[64 * 65];
    int tid = threadIdx.x;
    int b = blockIdx.x >> 5;
    int t0 = (blockIdx.x & 31) << 6;
    for (int r = 0; r < 16; r++) {
        int idx = tid + 256 * r;
        int c = idx >> 6, tt = idx & 63;
        t[c * 65 + tt] = x0[((size_t)b * 64 + c) * TL + t0 + tt];
    }
    __syncthreads();
    for (int r = 0; r < 16; r++) {
        int idx = tid + 256 * r;
        int tt = idx >> 6, c = idx & 63;
        X[((size_t)(t0 + tt)) * (NB * NH) + b * 64 + c] = t[c * 65 + tt];
    }
}

// ---------------- pipelined 10-layer LSTM: 512 thr = 2 groups, NO VGPR cap ----------------
// 2 waves/SIMD resident (172 VGPR x 2 = 344 <= 512/SIMD) -> cross-group latency hiding.
// Padded [136] LDS layout (round-5 proven; swizzle refuted by counters).
// Per-step fire-and-forget sc0sc1 ring stores; uniform counted vmcnt(10)/(2);
// superstep=8: per-wave vmcnt(40) + barrier -> deferred publish (t0) -> cached polls.
// V=0 full; V=1 noMFMA; V=2 noNONLIN; V=4 noRING+noSYNC (ablation probes).
template <int V>
__global__ __launch_bounds__(512) void k_lstm_t(
    const float* __restrict__ X0,
    const float* __restrict__ w_ih, const float* __restrict__ w_hh,
    const float* __restrict__ b_ih, const float* __restrict__ b_hh,
    unsigned* __restrict__ ring, float* __restrict__ final_h, int* prog, int tl)
{
    int bid = blockIdx.x;             // 0..19
    int layer = bid >> 1;
    int pair = bid & 1;
    if (layer >= NLAY) return;
    int tid = threadIdx.x;
    int g2 = tid >> 8;                // group within WG
    int tg = tid & 255;               // tid within group
    int wv = tg >> 6;                 // wave within group
    int lane = tid & 63;
    int l15 = lane & 15, l4 = lane >> 4;
    int u = wv * 16 + l15;
    int gidx = pair * 2 + g2;         // global group 0..3
    int b0 = gidx * 16;
    int self = layer * 4 + gidx;
    const bool has_store = (V != 4) && (layer < NLAY - 1);
    const bool use_ring = (V != 4) && (layer > 0);
    const bool do_sync = (V != 4);
    int brow = tg >> 4;
    int cc0 = (tg * 4) & 63;

    __shared__ __align__(16) unsigned short XH[2][2][16][136];  // [g2][buf][b][k]
    __shared__ __align__(16) unsigned short XL[2][2][16][136];

    // ---- weight fragments into registers ----
    bhalf8 Bh[4][4], Bl[4][4];
    float bias_v[4];
#pragma unroll
    for (int nt = 0; nt < 4; nt++) {
        int n = (nt * 4 + wv) * 16 + l15;
        const float* rih = w_ih + ((size_t)layer * 256 + n) * 64;
        const float* rhh = w_hh + ((size_t)layer * 256 + n) * 64;
        bias_v[nt] = b_ih[layer * 256 + n] + b_hh[layer * 256 + n];
#pragma unroll
        for (int kt = 0; kt < 4; kt++) {
#pragma unroll
            for (int j = 0; j < 8; j++) {
                int k = kt * 32 + l4 * 8 + j;
                float v = (k < 64) ? rih[k] : rhh[k - 64];
                unsigned short hb = f2bf(v);
                float lo = v - bf2f(hb);
                Bh[nt][kt][j] = (short)hb;
                Bl[nt][kt][j] = (short)f2bf(lo);
            }
        }
    }
    for (int idx = tid; idx < 2 * 2 * 16 * 136; idx += 512) {
        ((unsigned short*)XH)[idx] = 0;
        ((unsigned short*)XL)[idx] = 0;
    }
    float cst[4] = {0.f, 0.f, 0.f, 0.f};

    int* p_self = prog + self * 32;
    int* p_prev = prog + (self - 4) * 32;
    int* p_next = prog + (self + 4) * 32;
    int cached_prev = 0, cached_next = 0;

#define POLL_GE(ptr, tgt, cachev)                                                     \
    if (cachev < (tgt)) {                                                             \
        int v_; long g_ = 0;                                                          \
        while ((v_ = __hip_atomic_load(ptr, __ATOMIC_ACQUIRE,                         \
                        __HIP_MEMORY_SCOPE_AGENT)) < (tgt) && ++g_ < 1500000)         \
            __builtin_amdgcn_s_sleep(2);                                              \
        cachev = v_;                                                                  \
    }

    // ---- prologue: per-group wait prev>=16, stage x(0), preload x(1..3), drain ----
    if (do_sync && tg == 0 && layer > 0) { POLL_GE(p_prev, 16, cached_prev); }
    __syncthreads();
    f32x4 px[4];
    {
        f32x4 p0;
        if (!use_ring) {
            const float* s0 = X0 + (size_t)b0 * NH + tg * 4;
            asm volatile("global_load_dwordx4 %0, %1, off" : "=&v"(p0) : "v"(s0) : "memory");
        } else {
            const unsigned* s0 = ring + ((size_t)(layer - 1) * RSTEP) * 4096 + (b0 + brow) * 64 + cc0;
            asm volatile("global_load_dwordx4 %0, %1, off sc0 sc1" : "=&v"(p0) : "v"(s0) : "memory");
        }
        asm volatile("s_waitcnt vmcnt(0)" ::: "memory");
        __builtin_amdgcn_sched_barrier(0);
        bhalf4 hv, lv;
        if (!use_ring) {
#pragma unroll
            for (int j = 0; j < 4; j++) {
                unsigned short hb = f2bf(p0[j]);
                hv[j] = (short)hb;
                lv[j] = (short)f2bf(p0[j] - bf2f(hb));
            }
        } else {
#pragma unroll
            for (int j = 0; j < 4; j++) {
                unsigned w = __float_as_uint(p0[j]);
                hv[j] = (short)(unsigned short)(w >> 16);
                lv[j] = (short)(unsigned short)(w & 0xffffu);
            }
        }
        *(bhalf4*)&XH[g2][0][brow][cc0] = hv;
        *(bhalf4*)&XL[g2][0][brow][cc0] = lv;
#pragma unroll
        for (int pre = 1; pre <= 3; pre++) {
            if (!use_ring) {
                const float* sp = X0 + ((size_t)pre * NB + b0) * NH + tg * 4;
                asm volatile("global_load_dwordx4 %0, %1, off" : "=&v"(px[pre]) : "v"(sp) : "memory");
            } else {
                const unsigned* sp = ring + ((size_t)(layer - 1) * RSTEP + pre) * 4096 + (b0 + brow) * 64 + cc0;
                asm volatile("global_load_dwordx4 %0, %1, off sc0 sc1" : "=&v"(px[pre]) : "v"(sp) : "memory");
            }
        }
    }
    asm volatile("s_waitcnt vmcnt(0)" ::: "memory");
    __builtin_amdgcn_sched_barrier(0);
    __syncthreads();

    for (int t0 = 0; t0 < tl; t0 += 8) {
#pragma unroll
        for (int ts = 0; ts < 8; ++ts) {
            const int p = ts & 1, q = p ^ 1;
            const int t = t0 + ts;
            const int cons = (ts + 1) & 3;
            const int pref = ts & 3;

            // ---- gates: 3-term split precision, 8 independent chains ----
            f32x4 A0a = {bias_v[0], bias_v[0], bias_v[0], bias_v[0]};
            f32x4 A1a = {bias_v[1], bias_v[1], bias_v[1], bias_v[1]};
            f32x4 A2a = {bias_v[2], bias_v[2], bias_v[2], bias_v[2]};
            f32x4 A3a = {bias_v[3], bias_v[3], bias_v[3], bias_v[3]};
            f32x4 A0b = {0, 0, 0, 0}, A1b = {0, 0, 0, 0}, A2b = {0, 0, 0, 0}, A3b = {0, 0, 0, 0};
#pragma unroll
            for (int kt = 0; kt < 2; kt++) {
                bhalf8 Ah0 = *(const bhalf8*)&XH[g2][p][l15][kt * 32 + l4 * 8];
                bhalf8 Al0 = *(const bhalf8*)&XL[g2][p][l15][kt * 32 + l4 * 8];
                bhalf8 Ah1 = *(const bhalf8*)&XH[g2][p][l15][(kt + 2) * 32 + l4 * 8];
                bhalf8 Al1 = *(const bhalf8*)&XL[g2][p][l15][(kt + 2) * 32 + l4 * 8];
                if (V == 1) {
                    A0a[0] += (float)(int)Ah0[0] * 1e-20f;
                    A1a[0] += (float)(int)Ah1[0] * 1e-20f;
                    A2a[0] += (float)(int)Al0[0] * 1e-20f;
                    A3a[0] += (float)(int)Al1[0] * 1e-20f;
                } else {
                    A0a = __builtin_amdgcn_mfma_f32_16x16x32_bf16(Ah0, Bh[0][kt], A0a, 0, 0, 0);
                    A1a = __builtin_amdgcn_mfma_f32_16x16x32_bf16(Ah0, Bh[1][kt], A1a, 0, 0, 0);
                    A2a = __builtin_amdgcn_mfma_f32_16x16x32_bf16(Ah0, Bh[2][kt], A2a, 0, 0, 0);
                    A3a = __builtin_amdgcn_mfma_f32_16x16x32_bf16(Ah0, Bh[3][kt], A3a, 0, 0, 0);
                    A0b = __builtin_amdgcn_mfma_f32_16x16x32_bf16(Ah1, Bh[0][kt + 2], A0b, 0, 0, 0);
                    A1b = __builtin_amdgcn_mfma_f32_16x16x32_bf16(Ah1, Bh[1][kt + 2], A1b, 0, 0, 0);
                    A2b = __builtin_amdgcn_mfma_f32_16x16x32_bf16(Ah1, Bh[2][kt + 2], A2b, 0, 0, 0);
                    A3b = __builtin_amdgcn_mfma_f32_16x16x32_bf16(Ah1, Bh[3][kt + 2], A3b, 0, 0, 0);
                    A0a = __builtin_amdgcn_mfma_f32_16x16x32_bf16(Al0, Bh[0][kt], A0a, 0, 0, 0);
                    A1a = __builtin_amdgcn_mfma_f32_16x16x32_bf16(Al0, Bh[1][kt], A1a, 0, 0, 0);
                    A2a = __builtin_amdgcn_mfma_f32_16x16x32_bf16(Al0, Bh[2][kt], A2a, 0, 0, 0);
                    A3a = __builtin_amdgcn_mfma_f32_16x16x32_bf16(Al0, Bh[3][kt], A3a, 0, 0, 0);
                    A0b = __builtin_amdgcn_mfma_f32_16x16x32_bf16(Al1, Bh[0][kt + 2], A0b, 0, 0, 0);
                    A1b = __builtin_amdgcn_mfma_f32_16x16x32_bf16(Al1, Bh[1][kt + 2], A1b, 0, 0, 0);
                    A2b = __builtin_amdgcn_mfma_f32_16x16x32_bf16(Al1, Bh[2][kt + 2], A2b, 0, 0, 0);
                    A3b = __builtin_amdgcn_mfma_f32_16x16x32_bf16(Al1, Bh[3][kt + 2], A3b, 0, 0, 0);
                    A0a = __builtin_amdgcn_mfma_f32_16x16x32_bf16(Ah0, Bl[0][kt], A0a, 0, 0, 0);
                    A1a = __builtin_amdgcn_mfma_f32_16x16x32_bf16(Ah0, Bl[1][kt], A1a, 0, 0, 0);
                    A2a = __builtin_amdgcn_mfma_f32_16x16x32_bf16(Ah0, Bl[2][kt], A2a, 0, 0, 0);
                    A3a = __builtin_amdgcn_mfma_f32_16x16x32_bf16(Ah0, Bl[3][kt], A3a, 0, 0, 0);
                    A0b = __builtin_amdgcn_mfma_f32_16x16x32_bf16(Ah1, Bl[0][kt + 2], A0b, 0, 0, 0);
                    A1b = __builtin_amdgcn_mfma_f32_16x16x32_bf16(Ah1, Bl[1][kt + 2], A1b, 0, 0, 0);
                    A2b = __builtin_amdgcn_mfma_f32_16x16x32_bf16(Ah1, Bl[2][kt + 2], A2b, 0, 0, 0);
                    A3b = __builtin_amdgcn_mfma_f32_16x16x32_bf16(Ah1, Bl[3][kt + 2], A3b, 0, 0, 0);
                }
            }

            // ---- nonlinearity (V2: VALU-only stand-in, deps kept live) ----
            float hv4[4];
#pragma unroll
            for (int r = 0; r < 4; r++) {
                float gi = A0a[r] + A0b[r];
                float gf = A1a[r] + A1b[r];
                float gg = A2a[r] + A2b[r];
                float go = A3a[r] + A3b[r];
                if (V == 2) {
                    float c = fminf(fmaxf(0.1f * gf + 0.1f * gi + 0.1f * gg + 0.5f * cst[r], -1.f), 1.f);
                    cst[r] = c;
                    hv4[r] = fminf(fmaxf(0.1f * go + 0.5f * c, -1.f), 1.f);
                } else {
                    float c = fast_sigmoid(gf) * cst[r] + fast_sigmoid(gi) * fast_tanh(gg);
                    cst[r] = c;
                    hv4[r] = fast_sigmoid(go) * fast_tanh(c);
                }
            }

            // ---- uniform counted wait for x(t+1) only ----
            if (has_store) { asm volatile("s_waitcnt vmcnt(10)" ::: "memory"); }
            else           { asm volatile("s_waitcnt vmcnt(2)" ::: "memory"); }
            __builtin_amdgcn_sched_barrier(0);

            // ---- stage x(t+1) into buf q ----
            {
                bhalf4 hv, lv;
                if (!use_ring) {
#pragma unroll
                    for (int j = 0; j < 4; j++) {
                        unsigned short hb = f2bf(px[cons][j]);
                        hv[j] = (short)hb;
                        lv[j] = (short)f2bf(px[cons][j] - bf2f(hb));
                    }
                } else {
#pragma unroll
                    for (int j = 0; j < 4; j++) {
                        unsigned w = __float_as_uint(px[cons][j]);
                        hv[j] = (short)(unsigned short)(w >> 16);
                        lv[j] = (short)(unsigned short)(w & 0xffffu);
                    }
                }
                *(bhalf4*)&XH[g2][q][brow][cc0] = hv;
                *(bhalf4*)&XL[g2][q][brow][cc0] = lv;
            }

            // ---- own h into buf q; fire-and-forget ring stores ----
            unsigned pk[4];
#pragma unroll
            for (int r = 0; r < 4; r++) {
                int row = l4 * 4 + r;
                unsigned short hb = f2bf(hv4[r]);
                unsigned short lb = f2bf(hv4[r] - bf2f(hb));
                XH[g2][q][row][64 + u] = hb;
                XL[g2][q][row][64 + u] = lb;
                pk[r] = ((unsigned)hb << 16) | (unsigned)lb;
            }
            if (has_store) {
                unsigned* dst = ring + ((size_t)layer * RSTEP + (t & 63)) * 4096;
#pragma unroll
                for (int r = 0; r < 4; r++) {
                    unsigned* ap = dst + (b0 + l4 * 4 + r) * 64 + u;
                    asm volatile("global_store_dword %0, %1, off sc0 sc1" :: "v"(ap), "v"(pk[r]) : "memory");
                }
            } else if (layer == NLAY - 1 && t == tl - 1) {
#pragma unroll
                for (int r = 0; r < 4; r++)
                    final_h[(b0 + l4 * 4 + r) * NH + u] = hv4[r];
            }

            // ---- prefetch x(t+4) ----
            {
                int tt = t + 4; if (tt > tl - 1) tt = tl - 1;
                if (!use_ring) {
                    const float* sp = X0 + ((size_t)tt * NB + b0) * NH + tg * 4;
                    asm volatile("global_load_dwordx4 %0, %1, off" : "=&v"(px[pref]) : "v"(sp) : "memory");
                } else {
                    const unsigned* sp = ring + ((size_t)(layer - 1) * RSTEP + (tt & 63)) * 4096 + (b0 + brow) * 64 + cc0;
                    asm volatile("global_load_dwordx4 %0, %1, off sc0 sc1" : "=&v"(px[pref]) : "v"(sp) : "memory");
                }
            }

            asm volatile("s_waitcnt lgkmcnt(0)" ::: "memory");
            __builtin_amdgcn_s_barrier();
            __builtin_amdgcn_sched_barrier(0);
        }

        // ---- superstep end: per-wave counted drain, deferred publish (ALL layers), polls ----
        if (has_store) { asm volatile("s_waitcnt vmcnt(40)" ::: "memory"); }
        __builtin_amdgcn_s_barrier();
        __builtin_amdgcn_sched_barrier(0);
        if (do_sync && tg == 0) {
            __hip_atomic_store(p_self, t0, __ATOMIC_RELEASE, __HIP_MEMORY_SCOPE_AGENT);
            int nt0 = t0 + 8;
            if (nt0 < tl) {
                if (use_ring) {
                    int tgt = nt0 + 16; if (tgt > tl) tgt = tl;
                    POLL_GE(p_prev, tgt, cached_prev);
                }
                if (has_store) {
                    int need = nt0 - 48;
                    if (need > 0) { POLL_GE(p_next, need, cached_next); }
                }
            }
        }
        __builtin_amdgcn_s_barrier();
        __builtin_amdgcn_sched_barrier(0);
    }

    // ---- epilogue: full drain, final publish (ALL layers) ----
    asm volatile("s_waitcnt vmcnt(0)" ::: "memory");
    __builtin_amdgcn_s_barrier();
    if (do_sync && tg == 0) {
        __hip_atomic_store(p_self, tl, __ATOMIC_RELEASE, __HIP_MEMORY_SCOPE_AGENT);
    }
#undef POLL_GE
}

// ---------------- head ----------------
__global__ void k_head(const float* __restrict__ fh, const float* __restrict__ ow,
                       const float* __restrict__ ob, float* __restrict__ out)
{
    int b = threadIdx.x;
    if (b >= NB) return;
    const float* h = fh + b * NH;
    float l0 = ob[0], l1 = ob[1];
    for (int uu = 0; uu < 64; uu++) { l0 += h[uu] * ow[uu * 2]; l1 += h[uu] * ow[uu * 2 + 1]; }
    float m = fmaxf(l0, l1);
    float s = expf(l0 - m) + expf(l1 - m);
    float ls = m + logf(s);
    out[b * 2] = l0 - ls;
    out[b * 2 + 1] = l1 - ls;
}

extern "C" void kernel_launch(void* const* d_in, const int* in_sizes, int n_in,
                              void* d_out, int out_size, void* d_ws, size_t ws_size,
                              hipStream_t stream) {
    const float* input = (const float*)d_in[0];
    const float* c1w = (const float*)d_in[2];
    const float* c1b = (const float*)d_in[3];
    const float* c2w = (const float*)d_in[4];
    const float* c2b = (const float*)d_in[5];
    const float* bn1g = (const float*)d_in[6];
    const float* bn1b = (const float*)d_in[7];
    const float* bn1m = (const float*)d_in[8];
    const float* bn1v = (const float*)d_in[9];
    const float* rw1 = (const float*)d_in[10];
    const float* rb1 = (const float*)d_in[11];
    const float* bn2g = (const float*)d_in[12];
    const float* bn2b = (const float*)d_in[13];
    const float* bn2m = (const float*)d_in[14];
    const float* bn2v = (const float*)d_in[15];
    const float* rw2 = (const float*)d_in[16];
    const float* rb2 = (const float*)d_in[17];
    const float* wih = (const float*)d_in[18];
    const float* whh = (const float*)d_in[19];
    const float* bih = (const float*)d_in[20];
    const float* bhh = (const float*)d_in[21];
    const float* outw = (const float*)d_in[22];
    const float* outb = (const float*)d_in[23];

    float* ws = (float*)d_ws;
    float*    x0buf = ws;                          // [NB][64][TL]
    float*    t1buf = x0buf + 8388608;             // [NB][64][TL] (dead after transpose -> abl ring)
    float*    Xbuf  = t1buf + 8388608;             // [TL][NB][NH]
    unsigned* ringb = (unsigned*)(Xbuf + 8388608); // [9][64][64b][64u]
    float*    fhbuf = (float*)(ringb + 2359296);   // [NB][NH]
    float*    fhbuf2 = fhbuf + 4096;               // ablation dummy
    int*      progb = (int*)(fhbuf2 + 4096);       // 40 flags x 32
    int*      progb2 = progb + 40 * 32;            // ablation flags
    float*    wt1   = (float*)(progb2 + 40 * 32);
    float*    wt2   = wt1 + NRESU * 64 * 64 * 11;
    unsigned* ablring = (unsigned*)t1buf;          // reuse t1buf region

    hipMemsetAsync(progb, 0, 40 * 32 * sizeof(int), stream);

    k_prepw<<<528, 256, 0, stream>>>(rw1, wt1);
    k_prepw<<<528, 256, 0, stream>>>(rw2, wt2);
    k_frontend<<<2048, 256, 0, stream>>>(input, c1w, c1b, c2w, c2b, x0buf);
    for (int uu = 0; uu < NRESU; uu++) {
        k_resconv<<<1024, 256, 0, stream>>>(x0buf, t1buf, wt1 + uu * 45056, rb1 + uu * 64,
                                            bn1g + uu * 64, bn1b + uu * 64, bn1m + uu * 64, bn1v + uu * 64, 0);
        k_resconv<<<1024, 256, 0, stream>>>(t1buf, x0buf, wt2 + uu * 45056, rb2 + uu * 64,
                                            bn2g + uu * 64, bn2b + uu * 64, bn2m + uu * 64, bn2v + uu * 64, 1);
    }
    k_transpose<<<2048, 256, 0, stream>>>(x0buf, Xbuf);
    k_lstm_t<0><<<20, 512, 0, stream>>>(Xbuf, wih, whh, bih, bhh, ringb, fhbuf, progb, TL);
    k_head<<<1, 64, 0, stream>>>(fhbuf, outw, outb, (float*)d_out);

    // ---- ablation probes @ tl=2048 (visible in top-5; removed next round) ----
    hipMemsetAsync(progb2, 0, 40 * 32 * sizeof(int), stream);
    k_lstm_t<1><<<20, 512, 0, stream>>>(Xbuf, wih, whh, bih, bhh, ablring, fhbuf2, progb2, TL);
    hipMemsetAsync(progb2, 0, 40 * 32 * sizeof(int), stream);
    k_lstm_t<2><<<20, 512, 0, stream>>>(Xbuf, wih, whh, bih, bhh, ablring, fhbuf2, progb2, TL);
    hipMemsetAsync(progb2, 0, 40 * 32 * sizeof(int), stream);
    k_lstm_t<4><<<20, 512, 0, stream>>>(Xbuf, wih, whh, bih, bhh, ablring, fhbuf2, progb2, TL);
}

// Round 10
// 3499.139 us; speedup vs baseline: 3.7355x; 3.7355x over previous
//
#include <hip/hip_runtime.h>
#include <hip/hip_bf16.h>

#define TL 2048
#define NB 64
#define NH 64
#define NLAY 10
#define NRESU 3
#define RSTEP 64

typedef float f32x4 __attribute__((ext_vector_type(4)));
typedef unsigned u32x2 __attribute__((ext_vector_type(2)));
typedef unsigned u32x4 __attribute__((ext_vector_type(4)));
typedef short bhalf8 __attribute__((ext_vector_type(8)));
typedef short bhalf4 __attribute__((ext_vector_type(4)));

__device__ __forceinline__ unsigned short f2bf(float f) {
    unsigned u = __float_as_uint(f);
    unsigned r = u + 0x7fffu + ((u >> 16) & 1u);
    return (unsigned short)(r >> 16);
}
__device__ __forceinline__ float bf2f(unsigned short h) {
    return __uint_as_float(((unsigned)h) << 16);
}
__device__ __forceinline__ float fast_sigmoid(float x) {
    return __builtin_amdgcn_rcpf(1.0f + __expf(-x));
}
__device__ __forceinline__ float fast_tanh(float x) {
    float e = __expf(2.0f * x);
    return 1.0f - 2.0f * __builtin_amdgcn_rcpf(e + 1.0f);
}

// ---------------- frontend ----------------
__global__ __launch_bounds__(256) void k_frontend(
    const float* __restrict__ in,
    const float* __restrict__ c1w, const float* __restrict__ c1b,
    const float* __restrict__ c2w, const float* __restrict__ c2b,
    float* __restrict__ x0)
{
    __shared__ float s_c1w[128];
    __shared__ float s_c1b[32];
    __shared__ float s_c2w[64 * 33];
    __shared__ float s_c2b[64];
    __shared__ float h1[64 * 33];
    __shared__ float ot[64 * 65];
    int tid = threadIdx.x;
    int b = blockIdx.x >> 5;
    int l0 = (blockIdx.x & 31) << 6;
    if (tid < 128) s_c1w[tid] = c1w[tid];
    if (tid < 32) s_c1b[tid] = c1b[tid];
    if (tid < 64) s_c2b[tid] = c2b[tid];
    for (int r = tid; r < 2048; r += 256) s_c2w[(r >> 5) * 33 + (r & 31)] = c2w[r];
    __syncthreads();
    if (tid < 64) {
        const float* ip = in + ((size_t)b * TL + l0 + tid) * 4;
        float x0v = ip[0], x1 = ip[1], x2 = ip[2], x3 = ip[3];
#pragma unroll
        for (int o = 0; o < 32; o++) {
            float a = s_c1w[o * 4 + 0] * x0v + s_c1w[o * 4 + 1] * x1 +
                      s_c1w[o * 4 + 2] * x2 + s_c1w[o * 4 + 3] * x3 + s_c1b[o];
            h1[tid * 33 + o] = fmaxf(a, 0.0f);
        }
    }
    __syncthreads();
    {
        int o = tid & 63, lg = tid >> 6;
#pragma unroll
        for (int j = 0; j < 16; j++) {
            int l = lg * 16 + j;
            float a = s_c2b[o];
#pragma unroll
            for (int i = 0; i < 32; i++) a += h1[l * 33 + i] * s_c2w[o * 33 + i];
            ot[o * 65 + l] = fmaxf(a, 0.0f);
        }
    }
    __syncthreads();
    for (int r = 0; r < 16; r++) {
        int idx = tid + 256 * r;
        int c = idx >> 6, l = idx & 63;
        x0[((size_t)b * 64 + c) * TL + l0 + l] = ot[c * 65 + l];
    }
}

// ---------------- weight transpose for resconv ----------------
__global__ __launch_bounds__(256) void k_prepw(const float* __restrict__ w, float* __restrict__ wt)
{
    int idx = blockIdx.x * 256 + threadIdx.x;
    if (idx >= NRESU * 64 * 64 * 11) return;
    int k = idx % 11;
    int rest = idx / 11;
    int i = rest & 63;
    int o = (rest >> 6) & 63;
    int uu = rest >> 12;
    wt[(((size_t)uu * 64 + i) * 11 + k) * 64 + o] = w[idx];
}

// ---------------- residual conv k=11 pad=5 ----------------
__global__ __launch_bounds__(256) void k_resconv(
    const float* __restrict__ in, float* __restrict__ out,
    const float* __restrict__ wt, const float* __restrict__ bias,
    const float* __restrict__ bg, const float* __restrict__ bb,
    const float* __restrict__ bm, const float* __restrict__ bv,
    int accumulate)
{
    __shared__ float sscale[64], sshift[64];
    __shared__ float ht[64 * 139];
    int tid = threadIdx.x;
    int b = blockIdx.x >> 4;
    int l0 = (blockIdx.x & 15) << 7;
    if (tid < 64) {
        float sc = bg[tid] * rsqrtf(bv[tid] + 1e-5f);
        sscale[tid] = sc;
        sshift[tid] = bb[tid] - bm[tid] * sc;
    }
    __syncthreads();
    for (int r = 0; r < 35; r++) {
        int idx = tid + 256 * r;
        if (idx < 64 * 138) {
            int i = idx / 138, ll = idx - i * 138;
            int l = l0 - 5 + ll;
            float v = 0.0f;
            if (l >= 0 && l < TL) v = in[((size_t)b * 64 + i) * TL + l];
            ht[i * 139 + ll] = fmaxf(v * sscale[i] + sshift[i], 0.0f);
        }
    }
    __syncthreads();
    int o = tid & 63, lq = tid >> 6;
    float acc[32];
#pragma unroll
    for (int j = 0; j < 32; j++) acc[j] = 0.0f;
    for (int i = 0; i < 64; i++) {
        float wr[11];
#pragma unroll
        for (int k = 0; k < 11; k++) wr[k] = wt[(i * 11 + k) * 64 + o];
        float hr[42];
        const float* hp = ht + i * 139 + lq * 32;
#pragma unroll
        for (int k = 0; k < 42; k++) hr[k] = hp[k];
#pragma unroll
        for (int k = 0; k < 11; k++)
#pragma unroll
            for (int j = 0; j < 32; j++) acc[j] += hr[k + j] * wr[k];
    }
    float bsv = bias[o];
    float* op = out + ((size_t)b * 64 + o) * TL + l0 + lq * 32;
    if (accumulate) {
#pragma unroll
        for (int j = 0; j < 32; j++) op[j] += acc[j] + bsv;
    } else {
#pragma unroll
        for (int j = 0; j < 32; j++) op[j] = acc[j] + bsv;
    }
}

// ---------------- transpose+cast: [NB][64][TL] f32 -> [TL][NB*64] bf16 ----------------
__global__ __launch_bounds__(256) void k_transpose(
    const float* __restrict__ x0, unsigned short* __restrict__ Xbf)
{
    __shared__ float t[64 * 65];
    int tid = threadIdx.x;
    int b = blockIdx.x >> 5;
    int t0 = (blockIdx.x & 31) << 6;
    for (int r = 0; r < 16; r++) {
        int idx = tid + 256 * r;
        int c = idx >> 6, tt = idx & 63;
        t[c * 65 + tt] = x0[((size_t)b * 64 + c) * TL + t0 + tt];
    }
    __syncthreads();
    for (int r = 0; r < 16; r++) {
        int idx = tid + 256 * r;
        int tt = idx >> 6, c = idx & 63;
        Xbf[((size_t)(t0 + tt)) * (NB * NH) + b * 64 + c] = f2bf(t[c * 65 + tt]);
    }
}

// ---------------- pipelined 10-layer LSTM: bf16 1-term, 512 thr = 2 groups ----------------
// VGPR budget ~120 < the 128 cap hipcc applies to 512-thread blocks -> no spill,
// 2 waves/SIMD: group A's MFMA overlaps group B's transcendentals.
// X0 pre-cast to bf16 [t][b*64+u]; ring ushort [layer][t&63][b][u]; staging is a raw
// dwordx2 -> ds_write_b64 (zero conversion VALU). Protocol = round-8 proven:
// counted vmcnt(10)/(2) per step, vmcnt(40) superstep drain, deferred publish, polls.
__global__ __launch_bounds__(512) void k_lstm(
    const unsigned short* __restrict__ Xbf,
    const float* __restrict__ w_ih, const float* __restrict__ w_hh,
    const float* __restrict__ b_ih, const float* __restrict__ b_hh,
    unsigned short* __restrict__ ring, float* __restrict__ final_h, int* prog)
{
    int bid = blockIdx.x;             // 0..19
    int layer = bid >> 1;
    int pair = bid & 1;
    int tid = threadIdx.x;
    int g2 = tid >> 8;
    int tg = tid & 255;
    int wv = tg >> 6;
    int lane = tid & 63;
    int l15 = lane & 15, l4 = lane >> 4;
    int u = wv * 16 + l15;
    int gidx = pair * 2 + g2;
    int b0 = gidx * 16;
    int self = layer * 4 + gidx;
    const bool has_store = (layer < NLAY - 1);
    const bool use_ring = (layer > 0);
    int brow = tg >> 4;
    int cc0 = (tg * 4) & 63;

    __shared__ __align__(16) unsigned short XH[2][2][16][136];  // [g2][buf][b][x(64)|h(64)]

    // ---- weights (bf16 hi only) into registers ----
    bhalf8 Bh[4][4];
    float bias_v[4];
#pragma unroll
    for (int nt = 0; nt < 4; nt++) {
        int n = (nt * 4 + wv) * 16 + l15;
        const float* rih = w_ih + ((size_t)layer * 256 + n) * 64;
        const float* rhh = w_hh + ((size_t)layer * 256 + n) * 64;
        bias_v[nt] = b_ih[layer * 256 + n] + b_hh[layer * 256 + n];
#pragma unroll
        for (int kt = 0; kt < 4; kt++) {
#pragma unroll
            for (int j = 0; j < 8; j++) {
                int k = kt * 32 + l4 * 8 + j;
                float v = (k < 64) ? rih[k] : rhh[k - 64];
                Bh[nt][kt][j] = (short)f2bf(v);
            }
        }
    }
    for (int idx = tid; idx < 2 * 2 * 16 * 136; idx += 512) {
        ((unsigned short*)XH)[idx] = 0;
    }
    float cst[4] = {0.f, 0.f, 0.f, 0.f};

    int* p_self = prog + self * 32;
    int* p_prev = prog + (self - 4) * 32;
    int* p_next = prog + (self + 4) * 32;
    int cached_prev = 0, cached_next = 0;

#define POLL_GE(ptr, tgt, cachev)                                                     \
    if (cachev < (tgt)) {                                                             \
        int v_; long g_ = 0;                                                          \
        while ((v_ = __hip_atomic_load(ptr, __ATOMIC_ACQUIRE,                         \
                        __HIP_MEMORY_SCOPE_AGENT)) < (tgt) && ++g_ < 1500000)         \
            __builtin_amdgcn_s_sleep(2);                                              \
        cachev = v_;                                                                  \
    }

    // ---- prologue: wait prev>=16, stage x(0), preload x(1..3), drain ----
    if (tg == 0 && layer > 0) { POLL_GE(p_prev, 16, cached_prev); }
    __syncthreads();
    u32x2 px[4];
    {
        u32x2 p0;
        if (!use_ring) {
            const unsigned short* s0 = Xbf + (size_t)(b0 + brow) * 64 + cc0;
            asm volatile("global_load_dwordx2 %0, %1, off" : "=&v"(p0) : "v"(s0) : "memory");
        } else {
            const unsigned short* s0 = ring + ((size_t)(layer - 1) * RSTEP) * 4096 + (b0 + brow) * 64 + cc0;
            asm volatile("global_load_dwordx2 %0, %1, off sc0 sc1" : "=&v"(p0) : "v"(s0) : "memory");
        }
        asm volatile("s_waitcnt vmcnt(0)" ::: "memory");
        __builtin_amdgcn_sched_barrier(0);
        *(u32x2*)&XH[g2][0][brow][cc0] = p0;
#pragma unroll
        for (int pre = 1; pre <= 3; pre++) {
            if (!use_ring) {
                const unsigned short* sp = Xbf + ((size_t)pre * NB + b0 + brow) * 64 + cc0;
                asm volatile("global_load_dwordx2 %0, %1, off" : "=&v"(px[pre]) : "v"(sp) : "memory");
            } else {
                const unsigned short* sp = ring + ((size_t)(layer - 1) * RSTEP + pre) * 4096 + (b0 + brow) * 64 + cc0;
                asm volatile("global_load_dwordx2 %0, %1, off sc0 sc1" : "=&v"(px[pre]) : "v"(sp) : "memory");
            }
        }
    }
    asm volatile("s_waitcnt vmcnt(0)" ::: "memory");
    __builtin_amdgcn_sched_barrier(0);
    __syncthreads();

    for (int t0 = 0; t0 < TL; t0 += 8) {
#pragma unroll
        for (int ts = 0; ts < 8; ++ts) {
            const int p = ts & 1, q = p ^ 1;
            const int t = t0 + ts;
            const int cons = (ts + 1) & 3;   // px slot holding x(t+1)
            const int pref = ts & 3;         // slot to refill with x(t+4)

            // ---- gates = Xcat @ Wcat^T (bf16, fp32 accum), 4 chains, bias in init ----
            f32x4 A0 = {bias_v[0], bias_v[0], bias_v[0], bias_v[0]};
            f32x4 A1 = {bias_v[1], bias_v[1], bias_v[1], bias_v[1]};
            f32x4 A2 = {bias_v[2], bias_v[2], bias_v[2], bias_v[2]};
            f32x4 A3 = {bias_v[3], bias_v[3], bias_v[3], bias_v[3]};
#pragma unroll
            for (int kt = 0; kt < 4; kt++) {
                bhalf8 Ah = *(const bhalf8*)&XH[g2][p][l15][kt * 32 + l4 * 8];
                A0 = __builtin_amdgcn_mfma_f32_16x16x32_bf16(Ah, Bh[0][kt], A0, 0, 0, 0);
                A1 = __builtin_amdgcn_mfma_f32_16x16x32_bf16(Ah, Bh[1][kt], A1, 0, 0, 0);
                A2 = __builtin_amdgcn_mfma_f32_16x16x32_bf16(Ah, Bh[2][kt], A2, 0, 0, 0);
                A3 = __builtin_amdgcn_mfma_f32_16x16x32_bf16(Ah, Bh[3][kt], A3, 0, 0, 0);
            }

            // ---- lane-local nonlinearity (fp32) ----
            float hv4[4];
            unsigned short hb4[4];
#pragma unroll
            for (int r = 0; r < 4; r++) {
                float c = fast_sigmoid(A1[r]) * cst[r] + fast_sigmoid(A0[r]) * fast_tanh(A2[r]);
                cst[r] = c;
                float h = fast_sigmoid(A3[r]) * fast_tanh(c);
                hv4[r] = h;
                hb4[r] = f2bf(h);
            }

            // ---- counted wait for x(t+1) only (loaded 3 steps ago) ----
            if (has_store) { asm volatile("s_waitcnt vmcnt(10)" ::: "memory"); }
            else           { asm volatile("s_waitcnt vmcnt(2)" ::: "memory"); }
            __builtin_amdgcn_sched_barrier(0);

            // ---- stage x(t+1) into buf q (raw 8B copy, no VALU) ----
            *(u32x2*)&XH[g2][q][brow][cc0] = px[cons];

            // ---- own h into buf q; fire-and-forget ring stores (ushort) ----
#pragma unroll
            for (int r = 0; r < 4; r++) {
                XH[g2][q][l4 * 4 + r][64 + u] = hb4[r];
            }
            if (has_store) {
                unsigned short* dst = ring + ((size_t)layer * RSTEP + (t & 63)) * 4096;
#pragma unroll
                for (int r = 0; r < 4; r++) {
                    unsigned short* ap = dst + (b0 + l4 * 4 + r) * 64 + u;
                    unsigned val = hb4[r];
                    asm volatile("global_store_short %0, %1, off sc0 sc1" :: "v"(ap), "v"(val) : "memory");
                }
            } else if (t == TL - 1) {
#pragma unroll
                for (int r = 0; r < 4; r++)
                    final_h[(b0 + l4 * 4 + r) * NH + u] = hv4[r];
            }

            // ---- prefetch x(t+4) ----
            {
                int tt = t + 4; if (tt > TL - 1) tt = TL - 1;
                if (!use_ring) {
                    const unsigned short* sp = Xbf + ((size_t)tt * NB + b0 + brow) * 64 + cc0;
                    asm volatile("global_load_dwordx2 %0, %1, off" : "=&v"(px[pref]) : "v"(sp) : "memory");
                } else {
                    const unsigned short* sp = ring + ((size_t)(layer - 1) * RSTEP + (tt & 63)) * 4096 + (b0 + brow) * 64 + cc0;
                    asm volatile("global_load_dwordx2 %0, %1, off sc0 sc1" : "=&v"(px[pref]) : "v"(sp) : "memory");
                }
            }

            asm volatile("s_waitcnt lgkmcnt(0)" ::: "memory");
            __builtin_amdgcn_s_barrier();
            __builtin_amdgcn_sched_barrier(0);
        }

        // ---- superstep end: counted drain (own superstep's ops), publish, polls ----
        if (has_store) { asm volatile("s_waitcnt vmcnt(40)" ::: "memory"); }
        __builtin_amdgcn_s_barrier();
        __builtin_amdgcn_sched_barrier(0);
        if (tg == 0) {
            __hip_atomic_store(p_self, t0, __ATOMIC_RELEASE, __HIP_MEMORY_SCOPE_AGENT);
            int nt0 = t0 + 8;
            if (nt0 < TL) {
                if (use_ring) {
                    int tgt = nt0 + 16; if (tgt > TL) tgt = TL;
                    POLL_GE(p_prev, tgt, cached_prev);
                }
                if (has_store) {
                    int need = nt0 - 48;
                    if (need > 0) { POLL_GE(p_next, need, cached_next); }
                }
            }
        }
        __builtin_amdgcn_s_barrier();
        __builtin_amdgcn_sched_barrier(0);
    }

    // ---- epilogue: full drain, final publish ----
    asm volatile("s_waitcnt vmcnt(0)" ::: "memory");
    __builtin_amdgcn_s_barrier();
    if (tg == 0) {
        __hip_atomic_store(p_self, TL, __ATOMIC_RELEASE, __HIP_MEMORY_SCOPE_AGENT);
    }
#undef POLL_GE
}

// ---------------- head ----------------
__global__ void k_head(const float* __restrict__ fh, const float* __restrict__ ow,
                       const float* __restrict__ ob, float* __restrict__ out)
{
    int b = threadIdx.x;
    if (b >= NB) return;
    const float* h = fh + b * NH;
    float l0 = ob[0], l1 = ob[1];
    for (int uu = 0; uu < 64; uu++) { l0 += h[uu] * ow[uu * 2]; l1 += h[uu] * ow[uu * 2 + 1]; }
    float m = fmaxf(l0, l1);
    float s = expf(l0 - m) + expf(l1 - m);
    float ls = m + logf(s);
    out[b * 2] = l0 - ls;
    out[b * 2 + 1] = l1 - ls;
}

extern "C" void kernel_launch(void* const* d_in, const int* in_sizes, int n_in,
                              void* d_out, int out_size, void* d_ws, size_t ws_size,
                              hipStream_t stream) {
    const float* input = (const float*)d_in[0];
    const float* c1w = (const float*)d_in[2];
    const float* c1b = (const float*)d_in[3];
    const float* c2w = (const float*)d_in[4];
    const float* c2b = (const float*)d_in[5];
    const float* bn1g = (const float*)d_in[6];
    const float* bn1b = (const float*)d_in[7];
    const float* bn1m = (const float*)d_in[8];
    const float* bn1v = (const float*)d_in[9];
    const float* rw1 = (const float*)d_in[10];
    const float* rb1 = (const float*)d_in[11];
    const float* bn2g = (const float*)d_in[12];
    const float* bn2b = (const float*)d_in[13];
    const float* bn2m = (const float*)d_in[14];
    const float* bn2v = (const float*)d_in[15];
    const float* rw2 = (const float*)d_in[16];
    const float* rb2 = (const float*)d_in[17];
    const float* wih = (const float*)d_in[18];
    const float* whh = (const float*)d_in[19];
    const float* bih = (const float*)d_in[20];
    const float* bhh = (const float*)d_in[21];
    const float* outw = (const float*)d_in[22];
    const float* outb = (const float*)d_in[23];

    float* ws = (float*)d_ws;
    float*          x0buf = ws;                              // [NB][64][TL] f32
    float*          t1buf = x0buf + 8388608;                 // [NB][64][TL] f32
    unsigned short* Xbf   = (unsigned short*)(t1buf + 8388608);  // [TL][NB*64] bf16
    unsigned short* ringb = Xbf + 8388608;                   // [9][64][64b][64u] bf16
    float*          fhbuf = (float*)(ringb + 2359296);       // [NB][NH]
    int*            progb = (int*)(fhbuf + 4096);            // 40 flags x 32
    float*          wt1   = (float*)(progb + 40 * 32);
    float*          wt2   = wt1 + NRESU * 64 * 64 * 11;

    hipMemsetAsync(progb, 0, 40 * 32 * sizeof(int), stream);

    k_prepw<<<528, 256, 0, stream>>>(rw1, wt1);
    k_prepw<<<528, 256, 0, stream>>>(rw2, wt2);
    k_frontend<<<2048, 256, 0, stream>>>(input, c1w, c1b, c2w, c2b, x0buf);
    for (int uu = 0; uu < NRESU; uu++) {
        k_resconv<<<1024, 256, 0, stream>>>(x0buf, t1buf, wt1 + uu * 45056, rb1 + uu * 64,
                                            bn1g + uu * 64, bn1b + uu * 64, bn1m + uu * 64, bn1v + uu * 64, 0);
        k_resconv<<<1024, 256, 0, stream>>>(t1buf, x0buf, wt2 + uu * 45056, rb2 + uu * 64,
                                            bn2g + uu * 64, bn2b + uu * 64, bn2m + uu * 64, bn2v + uu * 64, 1);
    }
    k_transpose<<<2048, 256, 0, stream>>>(x0buf, Xbf);
    k_lstm<<<20, 512, 0, stream>>>(Xbf, wih, whh, bih, bhh, ringb, fhbuf, progb);
    k_head<<<1, 64, 0, stream>>>(fhbuf, outw, outb, (float*)d_out);
}